// Round 4
// baseline (348.838 us; speedup 1.0000x reference)
//
#include <hip/hip_runtime.h>

// VQ straight-through: B=32, V=4096, D=64, K=512. N = 131072 rows.
// Outputs (flat, concatenated): z_q_st [N,D] f32, z_q [N,D] f32, indices [N] (as f32).
//
// Correctness contract (established R2/R3, passing): replicate numpy fp32 bitwise —
//  - sums of squares: numpy pairwise_sum scalar 8-accumulator order, products
//    rounded separately (no FMA contraction into the sum)
//  - z@e.T dots: sequential single-accumulator FMA chain over d=0..63 (BLAS)
//  - d2 = fl(fl(A - 2*dot) + C); argmin k-ascending, strict < (first min)
//
// R4 perf changes vs R3 (177 us main, VALUBusy 70%, VGPR 40 => z[64] was
// rematerialized/reloaded from L1/L2 every k-group by LLVM's occupancy-greedy
// scheduler):
//  - amdgpu_waves_per_eu(4,4): pins the scheduler's occupancy target so the
//    128-VGPR budget is actually used; z[64] stays register-resident and the
//    k-loop body collapses to ~64 v_fmac + ~5 bookkeeping VALU per code.
//  - norms kernel fused into the main kernel (computed per-block into LDS,
//    overlapped with the z load / A-term; one dispatch instead of two).

#define VQ_N (32 * 4096)
#define VQ_D 64
#define VQ_K 512

// Rounding barrier: forbids FMA contraction / reassociation through x.
__device__ __forceinline__ float freeze(float x) {
  asm volatile("" : "+v"(x));
  return x;
}

__global__ __launch_bounds__(256) __attribute__((amdgpu_waves_per_eu(4, 4)))
void vq_main_kernel(const float* __restrict__ z_e,
                    const float* __restrict__ emb, float* __restrict__ out_st,
                    float* __restrict__ out_q, float* __restrict__ out_idx) {
  __shared__ float s_nrm[VQ_K];  // ||e_k||^2, numpy fp32 order
  __shared__ float s_val[256];   // per (chunk, row) partial best value
  __shared__ int s_idx[256];     // per (chunk, row) partial best index
  __shared__ int s_best[64];     // final best index per row

  const int tid = threadIdx.x;
  const int lane = tid & 63;                                   // row in block
  const int chunk = __builtin_amdgcn_readfirstlane(tid >> 6);  // wave-uniform
  const int row = blockIdx.x * 64 + lane;

  // ---- fused norms: C_k = np.sum(emb*emb, -1), 2 codes per thread ----
#pragma unroll
  for (int c = tid; c < VQ_K; c += 256) {
    const float* e = emb + (size_t)c * VQ_D;
    float r0 = freeze(e[0] * e[0]), r1 = freeze(e[1] * e[1]);
    float r2 = freeze(e[2] * e[2]), r3 = freeze(e[3] * e[3]);
    float r4 = freeze(e[4] * e[4]), r5 = freeze(e[5] * e[5]);
    float r6 = freeze(e[6] * e[6]), r7 = freeze(e[7] * e[7]);
#pragma unroll
    for (int i = 8; i < VQ_D; i += 8) {
      r0 += freeze(e[i + 0] * e[i + 0]); r1 += freeze(e[i + 1] * e[i + 1]);
      r2 += freeze(e[i + 2] * e[i + 2]); r3 += freeze(e[i + 3] * e[i + 3]);
      r4 += freeze(e[i + 4] * e[i + 4]); r5 += freeze(e[i + 5] * e[i + 5]);
      r6 += freeze(e[i + 6] * e[i + 6]); r7 += freeze(e[i + 7] * e[i + 7]);
    }
    s_nrm[c] = ((r0 + r1) + (r2 + r3)) + ((r4 + r5) + (r6 + r7));
  }

  // ---- row into registers (kept resident: ~64 VGPRs) ----
  float z[VQ_D];
  const float4* z4 = (const float4*)(z_e + (size_t)row * VQ_D);
#pragma unroll
  for (int j = 0; j < 16; ++j) {
    float4 v = z4[j];
    z[4 * j + 0] = v.x; z[4 * j + 1] = v.y;
    z[4 * j + 2] = v.z; z[4 * j + 3] = v.w;
  }

  // A = np.sum(z*z) in numpy 8-accumulator order; products rounded separately.
  float r0 = freeze(z[0] * z[0]), r1 = freeze(z[1] * z[1]);
  float r2 = freeze(z[2] * z[2]), r3 = freeze(z[3] * z[3]);
  float r4 = freeze(z[4] * z[4]), r5 = freeze(z[5] * z[5]);
  float r6 = freeze(z[6] * z[6]), r7 = freeze(z[7] * z[7]);
#pragma unroll
  for (int i = 8; i < VQ_D; i += 8) {
    r0 += freeze(z[i + 0] * z[i + 0]); r1 += freeze(z[i + 1] * z[i + 1]);
    r2 += freeze(z[i + 2] * z[i + 2]); r3 += freeze(z[i + 3] * z[i + 3]);
    r4 += freeze(z[i + 4] * z[i + 4]); r5 += freeze(z[i + 5] * z[i + 5]);
    r6 += freeze(z[i + 6] * z[i + 6]); r7 += freeze(z[i + 7] * z[i + 7]);
  }
  const float A = ((r0 + r1) + (r2 + r3)) + ((r4 + r5) + (r6 + r7));

  __syncthreads();  // s_nrm ready

  // ---- scan this wave's 128 codes, 4 at a time (4 independent FMA chains) ----
  const int k0 = chunk * (VQ_K / 4);
  float bestv = 3.4e38f;
  int best = k0;
  for (int kk = k0; kk < k0 + VQ_K / 4; kk += 4) {
    const float* e0 = emb + (size_t)(kk + 0) * VQ_D;
    const float* e1 = emb + (size_t)(kk + 1) * VQ_D;
    const float* e2 = emb + (size_t)(kk + 2) * VQ_D;
    const float* e3 = emb + (size_t)(kk + 3) * VQ_D;
    float a0 = 0.f, a1 = 0.f, a2 = 0.f, a3 = 0.f;
#pragma unroll
    for (int d = 0; d < VQ_D; ++d) {
      a0 = fmaf(z[d], e0[d], a0);  // sequential FMA, d ascending (BLAS order)
      a1 = fmaf(z[d], e1[d], a1);
      a2 = fmaf(z[d], e2[d], a2);
      a3 = fmaf(z[d], e3[d], a3);
    }
    // d2 = fl(fl(A - 2*dot) + C); 2*dot exact, so one rounding either way.
    float t0 = (A - 2.0f * a0) + s_nrm[kk + 0];
    float t1 = (A - 2.0f * a1) + s_nrm[kk + 1];
    float t2 = (A - 2.0f * a2) + s_nrm[kk + 2];
    float t3 = (A - 2.0f * a3) + s_nrm[kk + 3];
    if (t0 < bestv) { bestv = t0; best = kk + 0; }
    if (t1 < bestv) { bestv = t1; best = kk + 1; }
    if (t2 < bestv) { bestv = t2; best = kk + 2; }
    if (t3 < bestv) { bestv = t3; best = kk + 3; }
  }

  s_val[chunk * 64 + lane] = bestv;
  s_idx[chunk * 64 + lane] = best;
  __syncthreads();

  // Cross-chunk argmin per row: ascending chunk order + strict < keeps the
  // lowest-index minimum (chunk c's indices all < chunk c+1's) == np.argmin.
  if (tid < 64) {
    float v = s_val[tid];
    int b = s_idx[tid];
#pragma unroll
    for (int c = 1; c < 4; ++c) {
      float vc = s_val[c * 64 + tid];
      if (vc < v) { v = vc; b = s_idx[c * 64 + tid]; }
    }
    s_best[tid] = b;
    out_idx[row] = (float)b;
  }
  __syncthreads();

  // Coalesced output writes: 64 rows x 16 float4 per array.
  const float4* e4 = (const float4*)emb;
  const size_t base4 = (size_t)blockIdx.x * 64 * 16;
  float4* o0 = (float4*)out_st;
  float4* o1 = (float4*)out_q;
#pragma unroll
  for (int t = 0; t < 4; ++t) {
    int i = t * 256 + tid;
    int r = i >> 4, j = i & 15;
    float4 v = e4[s_best[r] * 16 + j];
    o0[base4 + i] = v;
    o1[base4 + i] = v;
  }
}

extern "C" void kernel_launch(void* const* d_in, const int* in_sizes, int n_in,
                              void* d_out, int out_size, void* d_ws,
                              size_t ws_size, hipStream_t stream) {
  const float* z_e = (const float*)d_in[0];  // [N, D] fp32
  const float* emb = (const float*)d_in[1];  // [K, D] fp32

  float* out_st = (float*)d_out;                 // [N, D]
  float* out_q = out_st + (size_t)VQ_N * VQ_D;   // [N, D]
  float* out_idx = out_q + (size_t)VQ_N * VQ_D;  // [N] as float

  vq_main_kernel<<<VQ_N / 64, 256, 0, stream>>>(z_e, emb, out_st, out_q,
                                                out_idx);
}

// Round 5
// 245.539 us; speedup vs baseline: 1.4207x; 1.4207x over previous
//
#include <hip/hip_runtime.h>

// VQ straight-through: B=32, V=4096, D=64, K=512. N = 131072 rows.
// Outputs (flat, concatenated): z_q_st [N,D] f32, z_q [N,D] f32, indices [N] (as f32).
//
// Correctness contract (established R2/R3, passing): replicate numpy fp32 bitwise —
//  - sums of squares: numpy pairwise_sum scalar 8-accumulator order, products
//    rounded separately (no FMA contraction into the sum)
//  - z@e.T dots: sequential single-accumulator FMA chain over d=0..63 (BLAS)
//  - d2 = fl(fl(A - 2*dot) + C); argmin k-ascending, strict < (first min)
//
// R5 vs R3 (177 us main, VALUBusy 70%, VGPR 40): R4's fused norms regressed
// (uncoalesced per-thread emb reads + barrier) -> reverted to R3's two-kernel
// structure. The one change: pin z[64] in VGPRs via an identity asm barrier
// INSIDE the k-loop. R3/R4 showed occupancy hints don't stop LLVM from
// rematerializing the z loads per k-group (VGPR stayed 40/52, ~16KB/wave L1
// reload per 4-code group). The asm redefines z each iteration, making it
// loop-carried through an opaque def -> reload is impossible, row stays
// register-resident. Zero instructions, numerics untouched.

#define VQ_N (32 * 4096)
#define VQ_D 64
#define VQ_K 512

// Rounding barrier: forbids FMA contraction / reassociation through x.
__device__ __forceinline__ float freeze(float x) {
  asm volatile("" : "+v"(x));
  return x;
}

// ---- kernel 1: C_k = np.sum(emb*emb, -1) in numpy fp32 order ----
__global__ __launch_bounds__(256) void vq_norms_kernel(
    const float* __restrict__ emb, float* __restrict__ nrm) {
  int k = blockIdx.x * blockDim.x + threadIdx.x;
  if (k < VQ_K) {
    const float* e = emb + k * VQ_D;
    float r0 = freeze(e[0] * e[0]), r1 = freeze(e[1] * e[1]);
    float r2 = freeze(e[2] * e[2]), r3 = freeze(e[3] * e[3]);
    float r4 = freeze(e[4] * e[4]), r5 = freeze(e[5] * e[5]);
    float r6 = freeze(e[6] * e[6]), r7 = freeze(e[7] * e[7]);
#pragma unroll
    for (int i = 8; i < VQ_D; i += 8) {
      r0 += freeze(e[i + 0] * e[i + 0]); r1 += freeze(e[i + 1] * e[i + 1]);
      r2 += freeze(e[i + 2] * e[i + 2]); r3 += freeze(e[i + 3] * e[i + 3]);
      r4 += freeze(e[i + 4] * e[i + 4]); r5 += freeze(e[i + 5] * e[i + 5]);
      r6 += freeze(e[i + 6] * e[i + 6]); r7 += freeze(e[i + 7] * e[i + 7]);
    }
    nrm[k] = ((r0 + r1) + (r2 + r3)) + ((r4 + r5) + (r6 + r7));
  }
}

// ---- kernel 2: main — 64 rows/block, K split across the 4 waves ----
__global__ __launch_bounds__(256) void vq_main_kernel(
    const float* __restrict__ z_e, const float* __restrict__ emb,
    const float* __restrict__ nrm, float* __restrict__ out_st,
    float* __restrict__ out_q, float* __restrict__ out_idx) {
  __shared__ float s_val[256];  // per (chunk, row) partial best value
  __shared__ int s_idx[256];    // per (chunk, row) partial best index
  __shared__ int s_best[64];    // final best index per row

  const int tid = threadIdx.x;
  const int lane = tid & 63;                                   // row in block
  const int chunk = __builtin_amdgcn_readfirstlane(tid >> 6);  // wave-uniform
  const int row = blockIdx.x * 64 + lane;

  // Row into registers.
  float z[VQ_D];
  const float4* z4 = (const float4*)(z_e + (size_t)row * VQ_D);
#pragma unroll
  for (int j = 0; j < 16; ++j) {
    float4 v = z4[j];
    z[4 * j + 0] = v.x; z[4 * j + 1] = v.y;
    z[4 * j + 2] = v.z; z[4 * j + 3] = v.w;
  }

  // A = np.sum(z*z) in numpy 8-accumulator order; products rounded separately.
  float r0 = freeze(z[0] * z[0]), r1 = freeze(z[1] * z[1]);
  float r2 = freeze(z[2] * z[2]), r3 = freeze(z[3] * z[3]);
  float r4 = freeze(z[4] * z[4]), r5 = freeze(z[5] * z[5]);
  float r6 = freeze(z[6] * z[6]), r7 = freeze(z[7] * z[7]);
#pragma unroll
  for (int i = 8; i < VQ_D; i += 8) {
    r0 += freeze(z[i + 0] * z[i + 0]); r1 += freeze(z[i + 1] * z[i + 1]);
    r2 += freeze(z[i + 2] * z[i + 2]); r3 += freeze(z[i + 3] * z[i + 3]);
    r4 += freeze(z[i + 4] * z[i + 4]); r5 += freeze(z[i + 5] * z[i + 5]);
    r6 += freeze(z[i + 6] * z[i + 6]); r7 += freeze(z[i + 7] * z[i + 7]);
  }
  const float A = ((r0 + r1) + (r2 + r3)) + ((r4 + r5) + (r6 + r7));

  // Scan this wave's 128 codes, 4 at a time (4 independent FMA chains).
  const int k0 = chunk * (VQ_K / 4);
  float bestv = 3.4e38f;
  int best = k0;
  for (int kk = k0; kk < k0 + VQ_K / 4; kk += 4) {
    // Residency pin: redefine z through an opaque identity each iteration so
    // the compiler cannot rematerialize the global loads inside the loop.
#pragma unroll
    for (int d = 0; d < VQ_D; ++d) asm volatile("" : "+v"(z[d]));

    const float* e0 = emb + (size_t)(kk + 0) * VQ_D;
    const float* e1 = emb + (size_t)(kk + 1) * VQ_D;
    const float* e2 = emb + (size_t)(kk + 2) * VQ_D;
    const float* e3 = emb + (size_t)(kk + 3) * VQ_D;
    float a0 = 0.f, a1 = 0.f, a2 = 0.f, a3 = 0.f;
#pragma unroll
    for (int d = 0; d < VQ_D; ++d) {
      a0 = fmaf(z[d], e0[d], a0);  // sequential FMA, d ascending (BLAS order)
      a1 = fmaf(z[d], e1[d], a1);
      a2 = fmaf(z[d], e2[d], a2);
      a3 = fmaf(z[d], e3[d], a3);
    }
    // d2 = fl(fl(A - 2*dot) + C); 2*dot exact => fmaf(-2,a,A) == fl(A-2a).
    float t0 = fmaf(-2.0f, a0, A) + nrm[kk + 0];
    float t1 = fmaf(-2.0f, a1, A) + nrm[kk + 1];
    float t2 = fmaf(-2.0f, a2, A) + nrm[kk + 2];
    float t3 = fmaf(-2.0f, a3, A) + nrm[kk + 3];
    if (t0 < bestv) { bestv = t0; best = kk + 0; }
    if (t1 < bestv) { bestv = t1; best = kk + 1; }
    if (t2 < bestv) { bestv = t2; best = kk + 2; }
    if (t3 < bestv) { bestv = t3; best = kk + 3; }
  }

  s_val[chunk * 64 + lane] = bestv;
  s_idx[chunk * 64 + lane] = best;
  __syncthreads();

  // Cross-chunk argmin per row: ascending chunk order + strict < keeps the
  // lowest-index minimum (chunk c's indices all < chunk c+1's) == np.argmin.
  if (tid < 64) {
    float v = s_val[tid];
    int b = s_idx[tid];
#pragma unroll
    for (int c = 1; c < 4; ++c) {
      float vc = s_val[c * 64 + tid];
      if (vc < v) { v = vc; b = s_idx[c * 64 + tid]; }
    }
    s_best[tid] = b;
    out_idx[row] = (float)b;
  }
  __syncthreads();

  // Coalesced output writes: 64 rows x 16 float4 per array.
  const float4* e4 = (const float4*)emb;
  const size_t base4 = (size_t)blockIdx.x * 64 * 16;
  float4* o0 = (float4*)out_st;
  float4* o1 = (float4*)out_q;
#pragma unroll
  for (int t = 0; t < 4; ++t) {
    int i = t * 256 + tid;
    int r = i >> 4, j = i & 15;
    float4 v = e4[s_best[r] * 16 + j];
    o0[base4 + i] = v;
    o1[base4 + i] = v;
  }
}

extern "C" void kernel_launch(void* const* d_in, const int* in_sizes, int n_in,
                              void* d_out, int out_size, void* d_ws,
                              size_t ws_size, hipStream_t stream) {
  const float* z_e = (const float*)d_in[0];  // [N, D] fp32
  const float* emb = (const float*)d_in[1];  // [K, D] fp32
  float* nrm = (float*)d_ws;                 // [K] fp32 scratch

  float* out_st = (float*)d_out;                 // [N, D]
  float* out_q = out_st + (size_t)VQ_N * VQ_D;   // [N, D]
  float* out_idx = out_q + (size_t)VQ_N * VQ_D;  // [N] as float

  vq_norms_kernel<<<(VQ_K + 255) / 256, 256, 0, stream>>>(emb, nrm);
  vq_main_kernel<<<VQ_N / 64, 256, 0, stream>>>(z_e, emb, nrm, out_st, out_q,
                                                out_idx);
}